// Round 6
// baseline (797.462 us; speedup 1.0000x reference)
//
#include <hip/hip_runtime.h>
#include <hip/hip_bf16.h>
#include <cstdint>
#include <cstddef>

#define ALPHA 0.2f
#define MLP_SLOPE 0.01f

typedef short bf16x8 __attribute__((ext_vector_type(8)));
typedef float f32x4 __attribute__((ext_vector_type(4)));
typedef unsigned short ushort_t;

__device__ __forceinline__ float lrelu(float x, float s) { return x > 0.f ? x : x * s; }
__device__ __forceinline__ ushort_t f2bf(float x) {
  __hip_bfloat16 h = __float2bfloat16(x);
  return *reinterpret_cast<ushort_t*>(&h);
}
__device__ __forceinline__ float bf2f(ushort_t u) {
  union { unsigned int i; float f; } v; v.i = ((unsigned int)u) << 16; return v.f;
}

// ---------------------------------------------------------------------------
// split fp32 -> (hi, lo) bf16, elementwise (4 elems/thread)
// ---------------------------------------------------------------------------
__global__ __launch_bounds__(256) void split_f(
    const float* __restrict__ in, ushort_t* __restrict__ hi,
    ushort_t* __restrict__ lo)
{
  int idx = blockIdx.x * 256 + threadIdx.x;
  float4 v = ((const float4*)in)[idx];
  ushort4 h, l;
  h.x = f2bf(v.x); l.x = f2bf(v.x - bf2f(h.x));
  h.y = f2bf(v.y); l.y = f2bf(v.y - bf2f(h.y));
  h.z = f2bf(v.z); l.z = f2bf(v.z - bf2f(h.z));
  h.w = f2bf(v.w); l.w = f2bf(v.w - bf2f(h.w));
  ((ushort4*)hi)[idx] = h;
  ((ushort4*)lo)[idx] = l;
}

// ---------------------------------------------------------------------------
// Pack weights W[K,N] (batch via blockIdx.y) into MFMA B-fragment order:
// out[((nblk*(K/32) + kblk)*64 + lane)*8 + e]
//   = W[(kblk*32 + (lane>>4)*8 + e)*N + nblk*16 + (lane&15)]   (hi/lo split)
// ---------------------------------------------------------------------------
__global__ __launch_bounds__(256) void pack_wt(
    const float* __restrict__ W, ushort_t* __restrict__ hi,
    ushort_t* __restrict__ lo, int K, int N)
{
  int gid = blockIdx.x * 256 + threadIdx.x;   // [0, N*K/8)
  int lane = gid & 63;
  int kbc = K >> 5;
  int kblk = (gid >> 6) % kbc;
  int nblk = (gid >> 6) / kbc;
  size_t b = (size_t)blockIdx.y * K * N;
  int col = nblk * 16 + (lane & 15);
  int krow = kblk * 32 + (lane >> 4) * 8;
  ushort_t h[8] __attribute__((aligned(16)));
  ushort_t l[8] __attribute__((aligned(16)));
#pragma unroll
  for (int e = 0; e < 8; ++e) {
    float v = W[b + (size_t)(krow + e) * N + col];
    h[e] = f2bf(v);
    l[e] = f2bf(v - bf2f(h[e]));
  }
  *(uint4*)&hi[b + (size_t)gid * 8] = *(uint4*)h;
  *(uint4*)&lo[b + (size_t)gid * 8] = *(uint4*)l;
}

// ---------------------------------------------------------------------------
// LDS-free split-bf16 MFMA GEMM: C = act(A[M,K] @ W + bias).
// A (hi/lo) read as fragments directly from global; W pre-packed in B-frag
// order (L2-resident). 3-pass hi/lo accum. Block 256 thr = 4 waves,
// block tile 128M x 64N, wave tile 64M x 32N. No LDS, no barriers.
// ---------------------------------------------------------------------------
__global__ __launch_bounds__(256) void gemm_nolds(
    const ushort_t* __restrict__ Ahi, const ushort_t* __restrict__ Alo,
    const ushort_t* __restrict__ Bph, const ushort_t* __restrict__ Bpl,
    const float* __restrict__ bias, float* __restrict__ Cf,
    ushort_t* __restrict__ Chi, ushort_t* __restrict__ Clo,
    int M, int N, int K, float slope, int act)
{
  const size_t boff = (size_t)blockIdx.z * N * K;
  const size_t coff = (size_t)blockIdx.z * M * N;
  const int t = threadIdx.x;
  const int wave = t >> 6, l63 = t & 63;
  const int l16 = t & 15, oct = (t >> 4) & 3, quad = oct;
  const int wm = (wave & 1) * 64, wn = (wave >> 1) * 32;
  const int m0 = blockIdx.y * 128 + wm;
  const int nb = blockIdx.x * 4 + (wave >> 1) * 2;
  const int nbase = blockIdx.x * 64 + wn;
  const int ksteps = K >> 5;

  const ushort_t* aph[4];
  const ushort_t* apl[4];
#pragma unroll
  for (int mt = 0; mt < 4; ++mt) {
    size_t o = (size_t)(m0 + mt * 16 + l16) * K + oct * 8;
    aph[mt] = Ahi + o;
    apl[mt] = Alo + o;
  }
  const ushort_t* bph[2];
  const ushort_t* bpl[2];
#pragma unroll
  for (int nt = 0; nt < 2; ++nt) {
    size_t o = boff + ((size_t)(nb + nt) * ksteps * 64 + l63) * 8;
    bph[nt] = Bph + o;
    bpl[nt] = Bpl + o;
  }

  f32x4 acc[4][2];
#pragma unroll
  for (int i = 0; i < 4; ++i)
#pragma unroll
    for (int j = 0; j < 2; ++j) acc[i][j] = (f32x4){0.f, 0.f, 0.f, 0.f};

#define LOADF(AH, AL, BH, BL, KB)                                         \
  {                                                                       \
    _Pragma("unroll") for (int mt = 0; mt < 4; ++mt) {                    \
      AH[mt] = *(const bf16x8*)(aph[mt] + (size_t)(KB) * 32);             \
      AL[mt] = *(const bf16x8*)(apl[mt] + (size_t)(KB) * 32);             \
    }                                                                     \
    _Pragma("unroll") for (int nt = 0; nt < 2; ++nt) {                    \
      BH[nt] = *(const bf16x8*)(bph[nt] + (size_t)(KB) * 512);            \
      BL[nt] = *(const bf16x8*)(bpl[nt] + (size_t)(KB) * 512);            \
    }                                                                     \
  }
#define MF(AH, AL, BH, BL)                                                \
  {                                                                       \
    _Pragma("unroll") for (int mt = 0; mt < 4; ++mt)                      \
    _Pragma("unroll") for (int nt = 0; nt < 2; ++nt) {                    \
      acc[mt][nt] = __builtin_amdgcn_mfma_f32_16x16x32_bf16(AH[mt], BH[nt], acc[mt][nt], 0, 0, 0); \
      acc[mt][nt] = __builtin_amdgcn_mfma_f32_16x16x32_bf16(AH[mt], BL[nt], acc[mt][nt], 0, 0, 0); \
      acc[mt][nt] = __builtin_amdgcn_mfma_f32_16x16x32_bf16(AL[mt], BH[nt], acc[mt][nt], 0, 0, 0); \
    }                                                                     \
  }

  bf16x8 ah0[4], al0[4], bh0[2], bl0[2];
  bf16x8 ah1[4], al1[4], bh1[2], bl1[2];
  LOADF(ah0, al0, bh0, bl0, 0)
  for (int kb = 0; kb < ksteps; kb += 2) {
    LOADF(ah1, al1, bh1, bl1, kb + 1)
    MF(ah0, al0, bh0, bl0)
    if (kb + 2 < ksteps) LOADF(ah0, al0, bh0, bl0, kb + 2)
    MF(ah1, al1, bh1, bl1)
  }
#undef LOADF
#undef MF

#pragma unroll
  for (int mt = 0; mt < 4; ++mt)
#pragma unroll
    for (int nt = 0; nt < 2; ++nt)
#pragma unroll
      for (int rg = 0; rg < 4; ++rg) {
        int m = m0 + mt * 16 + quad * 4 + rg;
        int n = nbase + nt * 16 + l16;
        float v = acc[mt][nt][rg];
        if (bias) v += bias[n];
        if (act) v = lrelu(v, slope);
        size_t o = coff + (size_t)m * N + n;
        if (Cf) Cf[o] = v;
        if (Chi) {
          ushort_t h = f2bf(v);
          Chi[o] = h; Clo[o] = f2bf(v - bf2f(h));
        }
      }
}

// ---------------------------------------------------------------------------
// s1/s2: per-row dots of h with a1/a2 (one wave per row, both heads)
// ---------------------------------------------------------------------------
__global__ __launch_bounds__(256) void s_kernel(
    const float* __restrict__ hbuf, const float* __restrict__ a1,
    const float* __restrict__ a2, float* __restrict__ s1, float* __restrict__ s2)
{
  const int gw = (blockIdx.x * 256 + threadIdx.x) >> 6;
  const int lane = threadIdx.x & 63;
#pragma unroll
  for (int hh = 0; hh < 2; ++hh) {
    float4 hv = ((const float4*)(hbuf + ((size_t)hh * 8192 + gw) * 256))[lane];
    float4 a1v = ((const float4*)(a1 + hh * 256))[lane];
    float4 a2v = ((const float4*)(a2 + hh * 256))[lane];
    float p1 = hv.x * a1v.x + hv.y * a1v.y + hv.z * a1v.z + hv.w * a1v.w;
    float p2 = hv.x * a2v.x + hv.y * a2v.y + hv.z * a2v.z + hv.w * a2v.w;
    for (int off = 32; off > 0; off >>= 1) {
      p1 += __shfl_xor(p1, off);
      p2 += __shfl_xor(p2, off);
    }
    if (lane == 0) {
      s1[hh * 8192 + gw] = p1;
      s2[hh * 8192 + gw] = p2;
    }
  }
}

// ---------------------------------------------------------------------------
// Pack h (fp32 [head][j][c]) into MFMA B-fragment order (bf16)
// ---------------------------------------------------------------------------
__global__ __launch_bounds__(256) void h_pack(
    const float* __restrict__ hbuf, ushort_t* __restrict__ Bpack)
{
  int gid = blockIdx.x * 256 + threadIdx.x;   // 0 .. 524287
  int lane = gid & 63;
  int ntile = (gid >> 6) & 15;
  int kblk = (gid >> 10) & 255;
  int head = gid >> 18;
  int c = ntile * 16 + (lane & 15);
  int jb = kblk * 32 + (lane >> 4) * 8;
  ushort_t o[8] __attribute__((aligned(16)));
#pragma unroll
  for (int e = 0; e < 8; ++e)
    o[e] = f2bf(hbuf[((size_t)head * 8192 + jb + e) * 256 + c]);
  *(uint4*)&Bpack[(size_t)gid * 8] = *(uint4*)o;
}

// ---------------------------------------------------------------------------
// MFMA attention v5: BARRIER-FREE, ZERO-DUP. Wave owns 16 rows (wq*16), BOTH
// heads, all 256 cols -> each lane owns exactly one adj row x 8 k: the block
// reads adj exactly once (R4's dup bug fixed by mapping, not by a barrier).
// W (A-frags) generated fully in-register; B-frags from L2/L3-resident Bpack
// via 3-slot rolling pipeline interleaved with MFMAs; adj/s2 prefetched one
// step ahead. No LDS, no __syncthreads anywhere.
// Block: 64 rows x 256 cols x 2 heads; grid (128 rowblocks, 4 k-slices).
// ---------------------------------------------------------------------------
__global__ __launch_bounds__(256, 2) void attn_mfma5(
    const ushort_t* __restrict__ Bpack, const float* __restrict__ s1g,
    const float* __restrict__ s2g, const int* __restrict__ adj,
    ushort_t* __restrict__ pacc, float* __restrict__ pl)
{
  const int t = threadIdx.x;
  const int i0 = blockIdx.x * 64;
  const int js = blockIdx.y;
  const int kbase = js * 2048;
  const int wq = t >> 6;                 // wave's 16-row strip
  const int l63 = t & 63;
  const int l16 = t & 15, oct = (t >> 4) & 3;
  const int row = i0 + wq * 16 + l16;    // this lane's unique W/adj row

  const float s1v0 = s1g[row];
  const float s1v1 = s1g[8192 + row];
  const int* arow = adj + (size_t)row * 8192;

  f32x4 acc[2][16];                      // [head][ntile]
#pragma unroll
  for (int h = 0; h < 2; ++h)
#pragma unroll
    for (int n = 0; n < 16; ++n) acc[h][n] = (f32x4){0.f, 0.f, 0.f, 0.f};
  float rs0 = 0.f, rs1 = 0.f;

  // prefetch step 0: this lane's adj octet (1 row) + s2 (both heads)
  int4 pa0, pa1;
  float4 p20a, p20b, p21a, p21b;
  {
    const int kk = kbase + oct * 8;
    pa0 = *(const int4*)&arow[kk];
    pa1 = *(const int4*)&arow[kk + 4];
    p20a = *(const float4*)&s2g[kk];
    p20b = *(const float4*)&s2g[kk + 4];
    p21a = *(const float4*)&s2g[8192 + kk];
    p21b = *(const float4*)&s2g[8192 + kk + 4];
  }

  for (int kt = 0; kt < 64; ++kt) {
    const int kblk = js * 64 + kt;
    const ushort_t* bb0 = Bpack + ((size_t)kblk * 16 * 64 + l63) * 8;  // head0
    const ushort_t* bb1 = bb0 + (size_t)256 * 16 * 64 * 8;             // head1

    bf16x8 Bf[3][4];
    auto loadg = [&](int g, int slot) {
      const ushort_t* p = (g < 4 ? bb0 : bb1) + (size_t)((g & 3) * 4) * 512;
#pragma unroll
      for (int i = 0; i < 4; ++i) Bf[slot][i] = *(const bf16x8*)(p + i * 512);
    };
    loadg(0, 0);
    loadg(1, 1);

    // ---- generate both heads' A-fragments in-register ----
    bf16x8 Af0, Af1;
    {
      int am[8] = {pa0.x, pa0.y, pa0.z, pa0.w, pa1.x, pa1.y, pa1.z, pa1.w};
      float s20[8] = {p20a.x, p20a.y, p20a.z, p20a.w, p20b.x, p20b.y, p20b.z, p20b.w};
      float s21[8] = {p21a.x, p21a.y, p21a.z, p21a.w, p21b.x, p21b.y, p21b.z, p21b.w};
      ushort_t w0[8] __attribute__((aligned(16)));
      ushort_t w1[8] __attribute__((aligned(16)));
#pragma unroll
      for (int e = 0; e < 8; ++e) {
        float e0 = s1v0 + s20[e];
        float e1 = s1v1 + s21[e];
        e0 = fmaxf(e0, 0.f) + ALPHA * fminf(e0, 0.f);
        e1 = fmaxf(e1, 0.f) + ALPHA * fminf(e1, 0.f);
        float v0 = am[e] > 0 ? __expf(e0) : 0.f;
        float v1 = am[e] > 0 ? __expf(e1) : 0.f;
        rs0 += v0; rs1 += v1;
        w0[e] = f2bf(v0); w1[e] = f2bf(v1);
      }
      Af0 = *(const bf16x8*)w0;
      Af1 = *(const bf16x8*)w1;
    }

    // ---- prefetch next step (HBM latency hidden under this step's MFMAs) ----
    if (kt < 63) {
      const int kk = kbase + (kt + 1) * 32 + oct * 8;
      pa0 = *(const int4*)&arow[kk];
      pa1 = *(const int4*)&arow[kk + 4];
      p20a = *(const float4*)&s2g[kk];
      p20b = *(const float4*)&s2g[kk + 4];
      p21a = *(const float4*)&s2g[8192 + kk];
      p21b = *(const float4*)&s2g[8192 + kk + 4];
    }

    // ---- MFMAs interleaved with rolling B-group loads ----
#pragma unroll
    for (int g = 0; g < 8; ++g) {
      if (g + 2 < 8) loadg(g + 2, (g + 2) % 3);
      const bf16x8 Af = (g < 4) ? Af0 : Af1;
      const int h = g >> 2, nb = (g & 3) * 4;
#pragma unroll
      for (int i = 0; i < 4; ++i)
        acc[h][nb + i] = __builtin_amdgcn_mfma_f32_16x16x32_bf16(
            Af, Bf[g % 3][i], acc[h][nb + i], 0, 0, 0);
    }
  }

  // ---- denominators: reduce across the 4 octs of each row ----
  rs0 += __shfl_xor(rs0, 16); rs0 += __shfl_xor(rs0, 32);
  rs1 += __shfl_xor(rs1, 16); rs1 += __shfl_xor(rs1, 32);
  if (oct == 0) {
    pl[((size_t)js * 2 + 0) * 8192 + row] = rs0;
    pl[((size_t)js * 2 + 1) * 8192 + row] = rs1;
  }

  // ---- store bf16 partial numerators (C-layout verified R2-R5) ----
#pragma unroll
  for (int h = 0; h < 2; ++h)
#pragma unroll
    for (int nt = 0; nt < 16; ++nt)
#pragma unroll
      for (int rg = 0; rg < 4; ++rg) {
        int r = i0 + wq * 16 + oct * 4 + rg;
        int c = nt * 16 + l16;
        pacc[(((size_t)js * 2 + h) * 8192 + r) * 256 + c] =
            f2bf(acc[h][nt][rg]);
      }
}

// ---------------------------------------------------------------------------
// Finalize (+ fused llm copy): sum 4 j-parts, /l, leaky_relu, l2-normalize,
// +bias, head-mean -> embed[:, 512:768]; embed[:, 0:512] = llm_emb.
// ---------------------------------------------------------------------------
__global__ __launch_bounds__(256) void attn_finalize(
    const ushort_t* __restrict__ pacc, const float* __restrict__ pl,
    const float* __restrict__ bg, const float* __restrict__ llm,
    float* __restrict__ embed)
{
  __shared__ float red[256];
  const int r = blockIdx.x;
  const int t = threadIdx.x;
  if (t < 128)
    *(float4*)&embed[(size_t)r * 768 + t * 4] =
        *(const float4*)&llm[(size_t)r * 512 + t * 4];
  float o[2], nrm[2];
#pragma unroll
  for (int hh = 0; hh < 2; ++hh) {
    float num = 0.f, l = 0.f;
#pragma unroll
    for (int js = 0; js < 4; ++js) {
      num += bf2f(pacc[(((size_t)js * 2 + hh) * 8192 + r) * 256 + t]);
      l += pl[((size_t)js * 2 + hh) * 8192 + r];
    }
    o[hh] = lrelu(num / l, ALPHA);
  }
  for (int hh = 0; hh < 2; ++hh) {
    __syncthreads();
    red[t] = o[hh] * o[hh];
    __syncthreads();
    for (int s = 128; s > 0; s >>= 1) {
      if (t < s) red[t] += red[t + s];
      __syncthreads();
    }
    nrm[hh] = fmaxf(sqrtf(red[0]), 1e-12f);
  }
  embed[(size_t)r * 768 + 512 + t] =
      0.5f * (o[0] / nrm[0] + bg[t] + o[1] / nrm[1] + bg[256 + t]);
}

// ---------------------------------------------------------------------------
__global__ __launch_bounds__(256) void pred_kernel(
    const float* __restrict__ z2, const int* __restrict__ ts,
    float* __restrict__ out, int E)
{
  const int gw = (blockIdx.x * 256 + threadIdx.x) >> 6;
  const int lane = threadIdx.x & 63;
  if (gw >= E) return;
  const int a = ts[gw * 2], b = ts[gw * 2 + 1];
  float4 va = ((const float4*)(z2 + (size_t)a * 256))[lane];
  float4 vb = ((const float4*)(z2 + (size_t)b * 256))[lane];
  float p = va.x * vb.x + va.y * vb.y + va.z * vb.z + va.w * vb.w;
  for (int off = 32; off > 0; off >>= 1) p += __shfl_xor(p, off);
  if (lane == 0) out[gw] = p;
}

// ---------------------------------------------------------------------------
extern "C" void kernel_launch(void* const* d_in, const int* in_sizes, int n_in,
                              void* d_out, int out_size, void* d_ws, size_t ws_size,
                              hipStream_t stream) {
  const float* x   = (const float*)d_in[0];
  const int*   adj = (const int*)d_in[1];
  const int*   ts  = (const int*)d_in[2];
  const float* llm = (const float*)d_in[3];
  const float* Wg  = (const float*)d_in[4];
  const float* a1  = (const float*)d_in[5];
  const float* a2  = (const float*)d_in[6];
  const float* bg  = (const float*)d_in[7];
  const float* W1  = (const float*)d_in[8];
  const float* b1  = (const float*)d_in[9];
  const float* W2  = (const float*)d_in[10];
  const float* b2  = (const float*)d_in[11];
  float* out = (float*)d_out;
  float* ws  = (float*)d_ws;
  const int E = in_sizes[2] / 2;

  // ---- workspace layout (float words), with lifetime overlays ----
  float*    hbuf  = ws;                             // [0, 4194304)
  ushort_t* Bpack = (ushort_t*)(ws + 4194304);      // [4194304, 6291456)
  float*    embed = ws;                             // overlay hbuf+Bpack
  ushort_t* xhi   = (ushort_t*)(ws + 6291456);
  ushort_t* xlo   = (ushort_t*)(ws + 8388608);
  ushort_t* z1hi  = xhi;                            // overlay (x dead)
  ushort_t* z1lo  = xlo;
  float*    s1    = ws + 10485760;
  float*    s2    = ws + 10502144;
  float*    pl    = ws + 10518528;
  ushort_t* pacc  = (ushort_t*)(ws + 10584064);
  ushort_t* ehi   = (ushort_t*)(ws + 10584064);     // overlay pacc (dead)
  ushort_t* elo   = (ushort_t*)(ws + 13729792);
  float*    z2    = ws + 16875520;
  ushort_t* wgphi = (ushort_t*)(ws + 18972672);     // 2*256*512
  ushort_t* wgplo = (ushort_t*)(ws + 19103744);
  ushort_t* w1phi = (ushort_t*)(ws + 19234816);     // 512*768
  ushort_t* w1plo = (ushort_t*)(ws + 19431424);
  ushort_t* w2phi = (ushort_t*)(ws + 19628032);     // 256*512
  ushort_t* w2plo = (ushort_t*)(ws + 19693568);

  // 1. splits / weight packing
  split_f<<<4096, 256, 0, stream>>>(x, xhi, xlo);
  pack_wt<<<dim3(64, 2), 256, 0, stream>>>(Wg, wgphi, wgplo, 512, 256);
  pack_wt<<<dim3(192, 1), 256, 0, stream>>>(W1, w1phi, w1plo, 768, 512);
  pack_wt<<<dim3(64, 1), 256, 0, stream>>>(W2, w2phi, w2plo, 512, 256);
  // 2. h[head] = x @ Wg[head]  (LDS-free split GEMM, fp32 out)
  gemm_nolds<<<dim3(4, 64, 2), 256, 0, stream>>>(
      xhi, xlo, wgphi, wgplo, nullptr, hbuf, nullptr, nullptr,
      8192, 256, 512, 0.f, 0);
  // 3. s1/s2 row dots
  s_kernel<<<2048, 256, 0, stream>>>(hbuf, a1, a2, s1, s2);
  // 4. pack h into B-fragment order
  h_pack<<<2048, 256, 0, stream>>>(hbuf, Bpack);
  // 5. MFMA attention partials (barrier-free, zero-dup)
  attn_mfma5<<<dim3(128, 4), 256, 0, stream>>>(Bpack, s1, s2, adj, pacc, pl);
  // 6. embed = [llm | attn epilogue]
  attn_finalize<<<8192, 256, 0, stream>>>(pacc, pl, bg, llm, embed);
  // 7. split embed (pacc dead now)
  split_f<<<6144, 256, 0, stream>>>(embed, ehi, elo);
  // 8. z1 = LR(embed @ W1 + b1) -> hi/lo bf16 directly
  gemm_nolds<<<dim3(8, 64, 1), 256, 0, stream>>>(
      ehi, elo, w1phi, w1plo, b1, nullptr, z1hi, z1lo,
      8192, 512, 768, MLP_SLOPE, 1);
  // 9. z2 = LR(z1 @ W2 + b2) fp32
  gemm_nolds<<<dim3(4, 64, 1), 256, 0, stream>>>(
      z1hi, z1lo, w2phi, w2plo, b2, z2, nullptr, nullptr,
      8192, 256, 512, MLP_SLOPE, 1);
  // 10. edge dots
  pred_kernel<<<(E * 64 + 255) / 256, 256, 0, stream>>>(z2, ts, out, E);
}

// Round 7
// 658.737 us; speedup vs baseline: 1.2106x; 1.2106x over previous
//
#include <hip/hip_runtime.h>
#include <hip/hip_bf16.h>
#include <cstdint>
#include <cstddef>

#define ALPHA 0.2f
#define MLP_SLOPE 0.01f

typedef short bf16x8 __attribute__((ext_vector_type(8)));
typedef float f32x4 __attribute__((ext_vector_type(4)));
typedef unsigned short ushort_t;

// raw barrier: syncs LDS exchange WITHOUT draining vmcnt (global prefetches
// stay in flight across it).
#define ASM_BARRIER() __asm__ __volatile__("s_waitcnt lgkmcnt(0)\n\ts_barrier" ::: "memory")

__device__ __forceinline__ float lrelu(float x, float s) { return x > 0.f ? x : x * s; }
__device__ __forceinline__ ushort_t f2bf(float x) {
  __hip_bfloat16 h = __float2bfloat16(x);
  return *reinterpret_cast<ushort_t*>(&h);
}
__device__ __forceinline__ float bf2f(ushort_t u) {
  union { unsigned int i; float f; } v; v.i = ((unsigned int)u) << 16; return v.f;
}

// ---------------------------------------------------------------------------
// split fp32 -> (hi, lo) bf16, elementwise (4 elems/thread)
// ---------------------------------------------------------------------------
__global__ __launch_bounds__(256) void split_f(
    const float* __restrict__ in, ushort_t* __restrict__ hi,
    ushort_t* __restrict__ lo)
{
  int idx = blockIdx.x * 256 + threadIdx.x;
  float4 v = ((const float4*)in)[idx];
  ushort4 h, l;
  h.x = f2bf(v.x); l.x = f2bf(v.x - bf2f(h.x));
  h.y = f2bf(v.y); l.y = f2bf(v.y - bf2f(h.y));
  h.z = f2bf(v.z); l.z = f2bf(v.z - bf2f(h.z));
  h.w = f2bf(v.w); l.w = f2bf(v.w - bf2f(h.w));
  ((ushort4*)hi)[idx] = h;
  ((ushort4*)lo)[idx] = l;
}

// ---------------------------------------------------------------------------
// Pack weights W[K,N] (batch via blockIdx.y) into MFMA B-fragment order
// ---------------------------------------------------------------------------
__global__ __launch_bounds__(256) void pack_wt(
    const float* __restrict__ W, ushort_t* __restrict__ hi,
    ushort_t* __restrict__ lo, int K, int N)
{
  int gid = blockIdx.x * 256 + threadIdx.x;   // [0, N*K/8)
  int lane = gid & 63;
  int kbc = K >> 5;
  int kblk = (gid >> 6) % kbc;
  int nblk = (gid >> 6) / kbc;
  size_t b = (size_t)blockIdx.y * K * N;
  int col = nblk * 16 + (lane & 15);
  int krow = kblk * 32 + (lane >> 4) * 8;
  ushort_t h[8] __attribute__((aligned(16)));
  ushort_t l[8] __attribute__((aligned(16)));
#pragma unroll
  for (int e = 0; e < 8; ++e) {
    float v = W[b + (size_t)(krow + e) * N + col];
    h[e] = f2bf(v);
    l[e] = f2bf(v - bf2f(h[e]));
  }
  *(uint4*)&hi[b + (size_t)gid * 8] = *(uint4*)h;
  *(uint4*)&lo[b + (size_t)gid * 8] = *(uint4*)l;
}

// ---------------------------------------------------------------------------
// LDS-free split-bf16 MFMA GEMM: C = act(A[M,K] @ W + bias).  (unchanged R5)
// ---------------------------------------------------------------------------
__global__ __launch_bounds__(256) void gemm_nolds(
    const ushort_t* __restrict__ Ahi, const ushort_t* __restrict__ Alo,
    const ushort_t* __restrict__ Bph, const ushort_t* __restrict__ Bpl,
    const float* __restrict__ bias, float* __restrict__ Cf,
    ushort_t* __restrict__ Chi, ushort_t* __restrict__ Clo,
    int M, int N, int K, float slope, int act)
{
  const size_t boff = (size_t)blockIdx.z * N * K;
  const size_t coff = (size_t)blockIdx.z * M * N;
  const int t = threadIdx.x;
  const int wave = t >> 6, l63 = t & 63;
  const int l16 = t & 15, oct = (t >> 4) & 3, quad = oct;
  const int wm = (wave & 1) * 64, wn = (wave >> 1) * 32;
  const int m0 = blockIdx.y * 128 + wm;
  const int nb = blockIdx.x * 4 + (wave >> 1) * 2;
  const int nbase = blockIdx.x * 64 + wn;
  const int ksteps = K >> 5;

  const ushort_t* aph[4];
  const ushort_t* apl[4];
#pragma unroll
  for (int mt = 0; mt < 4; ++mt) {
    size_t o = (size_t)(m0 + mt * 16 + l16) * K + oct * 8;
    aph[mt] = Ahi + o;
    apl[mt] = Alo + o;
  }
  const ushort_t* bph[2];
  const ushort_t* bpl[2];
#pragma unroll
  for (int nt = 0; nt < 2; ++nt) {
    size_t o = boff + ((size_t)(nb + nt) * ksteps * 64 + l63) * 8;
    bph[nt] = Bph + o;
    bpl[nt] = Bpl + o;
  }

  f32x4 acc[4][2];
#pragma unroll
  for (int i = 0; i < 4; ++i)
#pragma unroll
    for (int j = 0; j < 2; ++j) acc[i][j] = (f32x4){0.f, 0.f, 0.f, 0.f};

#define LOADF(AH, AL, BH, BL, KB)                                         \
  {                                                                       \
    _Pragma("unroll") for (int mt = 0; mt < 4; ++mt) {                    \
      AH[mt] = *(const bf16x8*)(aph[mt] + (size_t)(KB) * 32);             \
      AL[mt] = *(const bf16x8*)(apl[mt] + (size_t)(KB) * 32);             \
    }                                                                     \
    _Pragma("unroll") for (int nt = 0; nt < 2; ++nt) {                    \
      BH[nt] = *(const bf16x8*)(bph[nt] + (size_t)(KB) * 512);            \
      BL[nt] = *(const bf16x8*)(bpl[nt] + (size_t)(KB) * 512);            \
    }                                                                     \
  }
#define MF(AH, AL, BH, BL)                                                \
  {                                                                       \
    _Pragma("unroll") for (int mt = 0; mt < 4; ++mt)                      \
    _Pragma("unroll") for (int nt = 0; nt < 2; ++nt) {                    \
      acc[mt][nt] = __builtin_amdgcn_mfma_f32_16x16x32_bf16(AH[mt], BH[nt], acc[mt][nt], 0, 0, 0); \
      acc[mt][nt] = __builtin_amdgcn_mfma_f32_16x16x32_bf16(AH[mt], BL[nt], acc[mt][nt], 0, 0, 0); \
      acc[mt][nt] = __builtin_amdgcn_mfma_f32_16x16x32_bf16(AL[mt], BH[nt], acc[mt][nt], 0, 0, 0); \
    }                                                                     \
  }

  bf16x8 ah0[4], al0[4], bh0[2], bl0[2];
  bf16x8 ah1[4], al1[4], bh1[2], bl1[2];
  LOADF(ah0, al0, bh0, bl0, 0)
  for (int kb = 0; kb < ksteps; kb += 2) {
    LOADF(ah1, al1, bh1, bl1, kb + 1)
    MF(ah0, al0, bh0, bl0)
    if (kb + 2 < ksteps) LOADF(ah0, al0, bh0, bl0, kb + 2)
    MF(ah1, al1, bh1, bl1)
  }
#undef LOADF
#undef MF

#pragma unroll
  for (int mt = 0; mt < 4; ++mt)
#pragma unroll
    for (int nt = 0; nt < 2; ++nt)
#pragma unroll
      for (int rg = 0; rg < 4; ++rg) {
        int m = m0 + mt * 16 + quad * 4 + rg;
        int n = nbase + nt * 16 + l16;
        float v = acc[mt][nt][rg];
        if (bias) v += bias[n];
        if (act) v = lrelu(v, slope);
        size_t o = coff + (size_t)m * N + n;
        if (Cf) Cf[o] = v;
        if (Chi) {
          ushort_t h = f2bf(v);
          Chi[o] = h; Clo[o] = f2bf(v - bf2f(h));
        }
      }
}

// ---------------------------------------------------------------------------
// s1/s2: per-row dots of h with a1/a2 (one wave per row, both heads)
// ---------------------------------------------------------------------------
__global__ __launch_bounds__(256) void s_kernel(
    const float* __restrict__ hbuf, const float* __restrict__ a1,
    const float* __restrict__ a2, float* __restrict__ s1, float* __restrict__ s2)
{
  const int gw = (blockIdx.x * 256 + threadIdx.x) >> 6;
  const int lane = threadIdx.x & 63;
#pragma unroll
  for (int hh = 0; hh < 2; ++hh) {
    float4 hv = ((const float4*)(hbuf + ((size_t)hh * 8192 + gw) * 256))[lane];
    float4 a1v = ((const float4*)(a1 + hh * 256))[lane];
    float4 a2v = ((const float4*)(a2 + hh * 256))[lane];
    float p1 = hv.x * a1v.x + hv.y * a1v.y + hv.z * a1v.z + hv.w * a1v.w;
    float p2 = hv.x * a2v.x + hv.y * a2v.y + hv.z * a2v.z + hv.w * a2v.w;
    for (int off = 32; off > 0; off >>= 1) {
      p1 += __shfl_xor(p1, off);
      p2 += __shfl_xor(p2, off);
    }
    if (lane == 0) {
      s1[hh * 8192 + gw] = p1;
      s2[hh * 8192 + gw] = p2;
    }
  }
}

// ---------------------------------------------------------------------------
// Pack h (fp32 [head][j][c]) into MFMA B-fragment order (bf16)
// ---------------------------------------------------------------------------
__global__ __launch_bounds__(256) void h_pack(
    const float* __restrict__ hbuf, ushort_t* __restrict__ Bpack)
{
  int gid = blockIdx.x * 256 + threadIdx.x;   // 0 .. 524287
  int lane = gid & 63;
  int ntile = (gid >> 6) & 15;
  int kblk = (gid >> 10) & 255;
  int head = gid >> 18;
  int c = ntile * 16 + (lane & 15);
  int jb = kblk * 32 + (lane >> 4) * 8;
  ushort_t o[8] __attribute__((aligned(16)));
#pragma unroll
  for (int e = 0; e < 8; ++e)
    o[e] = f2bf(hbuf[((size_t)head * 8192 + jb + e) * 256 + c]);
  *(uint4*)&Bpack[(size_t)gid * 8] = *(uint4*)o;
}

// ---------------------------------------------------------------------------
// MFMA attention v6: R5's proven mapping (adj read ONCE per block by
// generator threads, coalesced; B-frags per-wave disjoint), but the K-loop is
// software-pipelined so W-gen executes in the MFMA shadow:
//   step kt: [issue B(kt)] [read Af(cur)] [MFMA x32]
//            [gen W(kt+1)->nxt buf] [prefetch adj/s2(kt+2)] [lgkm barrier]
// Gen-VALU overlaps the matrix pipe (within-wave different-pipe ILP +
// cross-wave co-issue); the barrier at step end finds LDS writes complete
// and leaves global prefetches in flight.
// ---------------------------------------------------------------------------
__global__ __launch_bounds__(256, 2) void attn_mfma6(
    const ushort_t* __restrict__ Bpack, const float* __restrict__ s1g,
    const float* __restrict__ s2g, const int* __restrict__ adj,
    ushort_t* __restrict__ pacc, float* __restrict__ pl)
{
  __shared__ ushort_t Wlds[2][2][4][64][8];   // [buf][head][mt][lane][8]
  const int t = threadIdx.x;
  const int i0 = blockIdx.x * 64;
  const int js = blockIdx.y;
  const int kbase = js * 2048;
  // generator mapping: row wr (0..63), k-octet kq (0..3) — coalesced adj
  const int wr = t >> 2, kq = t & 3;
  const int glane = kq * 16 + (wr & 15);
  const int gmt = wr >> 4;
  const float s1v0 = s1g[i0 + wr];
  const float s1v1 = s1g[8192 + i0 + wr];
  // consumer mapping
  const int wave = t >> 6, head = wave >> 1, nh = wave & 1;
  const int l16 = t & 15, quad = (t >> 4) & 3;
  const int l63 = t & 63;
  f32x4 acc[4][8];
#pragma unroll
  for (int m = 0; m < 4; ++m)
#pragma unroll
    for (int n = 0; n < 8; ++n) acc[m][n] = (f32x4){0.f, 0.f, 0.f, 0.f};
  float rs0 = 0.f, rs1 = 0.f;

  const int* arow = adj + (size_t)(i0 + wr) * 8192;
  int4 pa0, pa1;
  float4 p20a, p20b, p21a, p21b;

  auto fetch = [&](int kk) {
    pa0 = *(const int4*)&arow[kk];
    pa1 = *(const int4*)&arow[kk + 4];
    p20a = *(const float4*)&s2g[kk];
    p20b = *(const float4*)&s2g[kk + 4];
    p21a = *(const float4*)&s2g[8192 + kk];
    p21b = *(const float4*)&s2g[8192 + kk + 4];
  };
  auto gen = [&](int buf) {
    int am[8] = {pa0.x, pa0.y, pa0.z, pa0.w, pa1.x, pa1.y, pa1.z, pa1.w};
    float s20[8] = {p20a.x, p20a.y, p20a.z, p20a.w, p20b.x, p20b.y, p20b.z, p20b.w};
    float s21[8] = {p21a.x, p21a.y, p21a.z, p21a.w, p21b.x, p21b.y, p21b.z, p21b.w};
    ushort_t w0[8] __attribute__((aligned(16)));
    ushort_t w1[8] __attribute__((aligned(16)));
#pragma unroll
    for (int e = 0; e < 8; ++e) {
      float e0 = s1v0 + s20[e];
      float e1 = s1v1 + s21[e];
      e0 = fmaxf(e0, 0.f) + ALPHA * fminf(e0, 0.f);
      e1 = fmaxf(e1, 0.f) + ALPHA * fminf(e1, 0.f);
      float v0 = am[e] > 0 ? __expf(e0) : 0.f;
      float v1 = am[e] > 0 ? __expf(e1) : 0.f;
      rs0 += v0; rs1 += v1;
      w0[e] = f2bf(v0); w1[e] = f2bf(v1);
    }
    *(uint4*)&Wlds[buf][0][gmt][glane][0] = *(uint4*)w0;
    *(uint4*)&Wlds[buf][1][gmt][glane][0] = *(uint4*)w1;
  };

  // prologue: gen W(0) into buf0; start prefetch for step 1
  fetch(kbase + kq * 8);
  gen(0);
  fetch(kbase + 32 + kq * 8);
  ASM_BARRIER();

  for (int kt = 0; kt < 64; ++kt) {
    const int cur = kt & 1, nxt = cur ^ 1;
    // ---- issue B-fragment loads for this step (L2) ----
    const int kblk = js * 64 + kt;
    const ushort_t* bb =
        Bpack + ((((size_t)head * 256 + kblk) * 16 + nh * 8) * 64 + l63) * 8;
    bf16x8 Bf[8];
#pragma unroll
    for (int nt = 0; nt < 8; ++nt)
      Bf[nt] = *(const bf16x8*)&bb[nt * 512];
    // ---- read this step's A-fragments from LDS ----
    bf16x8 Af[4];
#pragma unroll
    for (int mt = 0; mt < 4; ++mt)
      Af[mt] = *(const bf16x8*)&Wlds[cur][head][mt][l63][0];
    // ---- MFMA burst; gen below overlaps via different-pipe ILP ----
#pragma unroll
    for (int mt = 0; mt < 4; ++mt)
#pragma unroll
      for (int nt = 0; nt < 8; ++nt)
        acc[mt][nt] = __builtin_amdgcn_mfma_f32_16x16x32_bf16(
            Af[mt], Bf[nt], acc[mt][nt], 0, 0, 0);
    // ---- generate next step's W into the other buffer ----
    if (kt < 63) {
      gen(nxt);
      if (kt < 62) fetch(kbase + (kt + 2) * 32 + kq * 8);
    }
    // ---- lgkm-only barrier: global prefetches stay in flight ----
    ASM_BARRIER();
  }

  // ---- denominators: reduce over the 4 kq-threads of each row ----
  rs0 += __shfl_xor(rs0, 1); rs0 += __shfl_xor(rs0, 2);
  rs1 += __shfl_xor(rs1, 1); rs1 += __shfl_xor(rs1, 2);
  if (kq == 0) {
    pl[((size_t)js * 2 + 0) * 8192 + i0 + wr] = rs0;
    pl[((size_t)js * 2 + 1) * 8192 + i0 + wr] = rs1;
  }
  // ---- store bf16 partial numerators ----
  const int n0 = nh * 128;
#pragma unroll
  for (int mt = 0; mt < 4; ++mt)
#pragma unroll
    for (int nt = 0; nt < 8; ++nt)
#pragma unroll
      for (int rg = 0; rg < 4; ++rg) {
        int row = i0 + mt * 16 + quad * 4 + rg;
        int col = n0 + nt * 16 + l16;
        pacc[(((size_t)js * 2 + head) * 8192 + row) * 256 + col] =
            f2bf(acc[mt][nt][rg]);
      }
}

// ---------------------------------------------------------------------------
// Finalize (+ fused llm copy): shuffle-based reduction, single barrier.
// ---------------------------------------------------------------------------
__global__ __launch_bounds__(256) void attn_finalize(
    const ushort_t* __restrict__ pacc, const float* __restrict__ pl,
    const float* __restrict__ bg, const float* __restrict__ llm,
    float* __restrict__ embed)
{
  __shared__ float red[8];
  const int r = blockIdx.x;
  const int t = threadIdx.x;
  const int wv = t >> 6, lane = t & 63;
  if (t < 128)
    *(float4*)&embed[(size_t)r * 768 + t * 4] =
        *(const float4*)&llm[(size_t)r * 512 + t * 4];
  float o[2];
#pragma unroll
  for (int hh = 0; hh < 2; ++hh) {
    float num = 0.f, l = 0.f;
#pragma unroll
    for (int js = 0; js < 4; ++js) {
      num += bf2f(pacc[(((size_t)js * 2 + hh) * 8192 + r) * 256 + t]);
      l += pl[((size_t)js * 2 + hh) * 8192 + r];
    }
    o[hh] = lrelu(num / l, ALPHA);
  }
  float v0 = o[0] * o[0], v1 = o[1] * o[1];
  for (int off = 32; off > 0; off >>= 1) {
    v0 += __shfl_xor(v0, off);
    v1 += __shfl_xor(v1, off);
  }
  if (lane == 0) { red[wv] = v0; red[4 + wv] = v1; }
  __syncthreads();
  float n0 = fmaxf(sqrtf(red[0] + red[1] + red[2] + red[3]), 1e-12f);
  float n1 = fmaxf(sqrtf(red[4] + red[5] + red[6] + red[7]), 1e-12f);
  embed[(size_t)r * 768 + 512 + t] =
      0.5f * (o[0] / n0 + bg[t] + o[1] / n1 + bg[256 + t]);
}

// ---------------------------------------------------------------------------
__global__ __launch_bounds__(256) void pred_kernel(
    const float* __restrict__ z2, const int* __restrict__ ts,
    float* __restrict__ out, int E)
{
  const int gw = (blockIdx.x * 256 + threadIdx.x) >> 6;
  const int lane = threadIdx.x & 63;
  if (gw >= E) return;
  const int a = ts[gw * 2], b = ts[gw * 2 + 1];
  float4 va = ((const float4*)(z2 + (size_t)a * 256))[lane];
  float4 vb = ((const float4*)(z2 + (size_t)b * 256))[lane];
  float p = va.x * vb.x + va.y * vb.y + va.z * vb.z + va.w * vb.w;
  for (int off = 32; off > 0; off >>= 1) p += __shfl_xor(p, off);
  if (lane == 0) out[gw] = p;
}

// ---------------------------------------------------------------------------
extern "C" void kernel_launch(void* const* d_in, const int* in_sizes, int n_in,
                              void* d_out, int out_size, void* d_ws, size_t ws_size,
                              hipStream_t stream) {
  const float* x   = (const float*)d_in[0];
  const int*   adj = (const int*)d_in[1];
  const int*   ts  = (const int*)d_in[2];
  const float* llm = (const float*)d_in[3];
  const float* Wg  = (const float*)d_in[4];
  const float* a1  = (const float*)d_in[5];
  const float* a2  = (const float*)d_in[6];
  const float* bg  = (const float*)d_in[7];
  const float* W1  = (const float*)d_in[8];
  const float* b1  = (const float*)d_in[9];
  const float* W2  = (const float*)d_in[10];
  const float* b2  = (const float*)d_in[11];
  float* out = (float*)d_out;
  float* ws  = (float*)d_ws;
  const int E = in_sizes[2] / 2;

  // ---- workspace layout (float words), with lifetime overlays ----
  float*    hbuf  = ws;                             // [0, 4194304)
  ushort_t* Bpack = (ushort_t*)(ws + 4194304);      // [4194304, 6291456)
  float*    embed = ws;                             // overlay hbuf+Bpack
  ushort_t* xhi   = (ushort_t*)(ws + 6291456);
  ushort_t* xlo   = (ushort_t*)(ws + 8388608);
  ushort_t* z1hi  = xhi;                            // overlay (x dead)
  ushort_t* z1lo  = xlo;
  float*    s1    = ws + 10485760;
  float*    s2    = ws + 10502144;
  float*    pl    = ws + 10518528;
  ushort_t* pacc  = (ushort_t*)(ws + 10584064);
  ushort_t* ehi   = (ushort_t*)(ws + 10584064);     // overlay pacc (dead)
  ushort_t* elo   = (ushort_t*)(ws + 13729792);
  float*    z2    = ws + 16875520;
  ushort_t* wgphi = (ushort_t*)(ws + 18972672);     // 2*256*512
  ushort_t* wgplo = (ushort_t*)(ws + 19103744);
  ushort_t* w1phi = (ushort_t*)(ws + 19234816);     // 512*768
  ushort_t* w1plo = (ushort_t*)(ws + 19431424);
  ushort_t* w2phi = (ushort_t*)(ws + 19628032);     // 256*512
  ushort_t* w2plo = (ushort_t*)(ws + 19693568);

  // 1. splits / weight packing
  split_f<<<4096, 256, 0, stream>>>(x, xhi, xlo);
  pack_wt<<<dim3(64, 2), 256, 0, stream>>>(Wg, wgphi, wgplo, 512, 256);
  pack_wt<<<dim3(192, 1), 256, 0, stream>>>(W1, w1phi, w1plo, 768, 512);
  pack_wt<<<dim3(64, 1), 256, 0, stream>>>(W2, w2phi, w2plo, 512, 256);
  // 2. h[head] = x @ Wg[head]  (LDS-free split GEMM, fp32 out)
  gemm_nolds<<<dim3(4, 64, 2), 256, 0, stream>>>(
      xhi, xlo, wgphi, wgplo, nullptr, hbuf, nullptr, nullptr,
      8192, 256, 512, 0.f, 0);
  // 3. s1/s2 row dots
  s_kernel<<<2048, 256, 0, stream>>>(hbuf, a1, a2, s1, s2);
  // 4. pack h into B-fragment order
  h_pack<<<2048, 256, 0, stream>>>(hbuf, Bpack);
  // 5. MFMA attention partials (software-pipelined gen-in-MFMA-shadow)
  attn_mfma6<<<dim3(128, 4), 256, 0, stream>>>(Bpack, s1, s2, adj, pacc, pl);
  // 6. embed = [llm | attn epilogue]
  attn_finalize<<<8192, 256, 0, stream>>>(pacc, pl, bg, llm, embed);
  // 7. split embed (pacc dead now)
  split_f<<<6144, 256, 0, stream>>>(embed, ehi, elo);
  // 8. z1 = LR(embed @ W1 + b1) -> hi/lo bf16 directly
  gemm_nolds<<<dim3(8, 64, 1), 256, 0, stream>>>(
      ehi, elo, w1phi, w1plo, b1, nullptr, z1hi, z1lo,
      8192, 512, 768, MLP_SLOPE, 1);
  // 9. z2 = LR(z1 @ W2 + b2) fp32
  gemm_nolds<<<dim3(4, 64, 1), 256, 0, stream>>>(
      z1hi, z1lo, w2phi, w2plo, b2, z2, nullptr, nullptr,
      8192, 256, 512, MLP_SLOPE, 1);
  // 10. edge dots
  pred_kernel<<<(E * 64 + 255) / 256, 256, 0, stream>>>(z2, ts, out, E);
}